// Round 1
// baseline (1962.558 us; speedup 1.0000x reference)
//
#include <hip/hip_runtime.h>
#include <math.h>

// Problem constants: B=2, T=2048, C=1024, H=16, D=64
constexpr int Bb = 2;
constexpr int Tt = 2048;
constexpr int Cc = 1024;
constexpr int Hh = 16;
constexpr int Dd = 64;
constexpr int M_ROWS = Bb * Tt;          // 4096
constexpr float EPSV = 1e-5f;

// ---------------------------------------------------------------------------
// RoPE tables: cos/sin [T][32]
// ---------------------------------------------------------------------------
__global__ __launch_bounds__(64) void rope_tables_k(float* __restrict__ cosT,
                                                    float* __restrict__ sinT) {
    int tid = threadIdx.x;
    int t = blockIdx.x * 2 + (tid >> 5);   // grid 1024 blocks -> t in [0,2048)
    int j = tid & 31;
    float inv = exp2f(-(float)j * (log2f(10000.0f) / 32.0f));
    float a = (float)t * inv;
    cosT[t * 32 + j] = cosf(a);
    sinT[t * 32 + j] = sinf(a);
}

// ---------------------------------------------------------------------------
// RMSNorm: one block per row of C=1024; 256 threads x float4
// ---------------------------------------------------------------------------
__global__ __launch_bounds__(256) void rmsnorm_k(const float* __restrict__ x,
                                                 const float* __restrict__ w,
                                                 float* __restrict__ xn) {
    int row = blockIdx.x;
    int tid = threadIdx.x;
    const float* xr = x + (size_t)row * Cc;
    float4 v = *(const float4*)&xr[tid * 4];
    float ss = v.x * v.x + v.y * v.y + v.z * v.z + v.w * v.w;
    #pragma unroll
    for (int off = 32; off > 0; off >>= 1) ss += __shfl_down(ss, off);
    __shared__ float ws_[4];
    if ((tid & 63) == 0) ws_[tid >> 6] = ss;
    __syncthreads();
    float tot = ws_[0] + ws_[1] + ws_[2] + ws_[3];
    float r = rsqrtf(tot * (1.0f / (float)Cc) + EPSV);
    float4 wv = *(const float4*)&w[tid * 4];
    float4 o;
    o.x = v.x * r * wv.x;
    o.y = v.y * r * wv.y;
    o.z = v.z * r * wv.z;
    o.w = v.w * r * wv.w;
    *(float4*)&xn[(size_t)row * Cc + tid * 4] = o;
}

// ---------------------------------------------------------------------------
// Tiled fp32 GEMM: O[M][N] = A[M][K] * W[N][K]^T + bias[N]
// 64x64 tile, BK=16, 256 threads, 4x4 microtile per thread.
// ---------------------------------------------------------------------------
__global__ __launch_bounds__(256) void gemm_bias_k(const float* __restrict__ A,
                                                   const float* __restrict__ W,
                                                   const float* __restrict__ bias,
                                                   float* __restrict__ O,
                                                   int M, int N, int K) {
    __shared__ float As[16][68];
    __shared__ float Bs[16][68];
    int tid = threadIdx.x;
    int m0 = blockIdx.y * 64;
    int n0 = blockIdx.x * 64;
    int lr = tid >> 2;          // 0..63 row within tile
    int lc = (tid & 3) * 4;     // k offset {0,4,8,12}
    int tx = (tid & 15) * 4;    // output col offset
    int ty = (tid >> 4) * 4;    // output row offset
    float acc[4][4] = {};
    for (int k0 = 0; k0 < K; k0 += 16) {
        float4 av = *(const float4*)&A[(size_t)(m0 + lr) * K + k0 + lc];
        float4 bv = *(const float4*)&W[(size_t)(n0 + lr) * K + k0 + lc];
        __syncthreads();
        As[lc + 0][lr] = av.x; As[lc + 1][lr] = av.y;
        As[lc + 2][lr] = av.z; As[lc + 3][lr] = av.w;
        Bs[lc + 0][lr] = bv.x; Bs[lc + 1][lr] = bv.y;
        Bs[lc + 2][lr] = bv.z; Bs[lc + 3][lr] = bv.w;
        __syncthreads();
        #pragma unroll
        for (int k = 0; k < 16; ++k) {
            float4 a4 = *(const float4*)&As[k][ty];
            float4 b4 = *(const float4*)&Bs[k][tx];
            float ar[4] = {a4.x, a4.y, a4.z, a4.w};
            float br[4] = {b4.x, b4.y, b4.z, b4.w};
            #pragma unroll
            for (int i = 0; i < 4; ++i)
                #pragma unroll
                for (int j = 0; j < 4; ++j)
                    acc[i][j] += ar[i] * br[j];
        }
    }
    float4 bvv = *(const float4*)&bias[n0 + tx];
    float bb[4] = {bvv.x, bvv.y, bvv.z, bvv.w};
    #pragma unroll
    for (int i = 0; i < 4; ++i) {
        float4 o;
        o.x = acc[i][0] + bb[0];
        o.y = acc[i][1] + bb[1];
        o.z = acc[i][2] + bb[2];
        o.w = acc[i][3] + bb[3];
        *(float4*)&O[(size_t)(m0 + ty + i) * N + n0 + tx] = o;
    }
}

// ---------------------------------------------------------------------------
// RoPE in-place on q and k planes of qkv [B,T,3,H,D]
// One thread per (b,t,{q,k},h,pair d<32): 4,194,304 threads.
// ---------------------------------------------------------------------------
__global__ __launch_bounds__(256) void rope_apply_k(float* __restrict__ qkv,
                                                    const float* __restrict__ cosT,
                                                    const float* __restrict__ sinT) {
    int idx = blockIdx.x * 256 + threadIdx.x;
    int d = idx & 31;  int w = idx >> 5;
    int h = w & 15;    w >>= 4;
    int s = w & 1;     w >>= 1;
    int t = w & 2047;  int b = w >> 11;
    float* p = qkv + ((size_t)(b * Tt + t)) * (3 * Cc) + s * Cc + h * Dd + d;
    float c  = cosT[t * 32 + d];
    float sn = sinT[t * 32 + d];
    float x0 = p[0];
    float x1 = p[32];
    p[0]  = x0 * c - x1 * sn;
    p[32] = x1 * c + x0 * sn;
}

// ---------------------------------------------------------------------------
// Flash-style causal attention, fp32. One wave (64 threads) per
// (b, h, q-tile of 64 rows); each thread owns one q row.
// ---------------------------------------------------------------------------
__global__ __launch_bounds__(64) void attn_k(const float* __restrict__ qkv,
                                             float* __restrict__ out) {
    int qt = blockIdx.x;   // 0..31
    int h  = blockIdx.y;   // 0..15
    int b  = blockIdx.z;   // 0..1
    int tid = threadIdx.x; // 0..63
    int qg = qt * 64 + tid;

    __shared__ float Ks[64][68];
    __shared__ float Vs[64][68];

    const float* qb = qkv + ((size_t)(b * Tt + qg)) * (3 * Cc) + h * Dd;
    float4 q4[16], a4[16];
    #pragma unroll
    for (int i = 0; i < 16; ++i) {
        q4[i] = *(const float4*)&qb[i * 4];
        a4[i] = make_float4(0.f, 0.f, 0.f, 0.f);
    }
    float m = -INFINITY, l = 0.f;

    for (int j = 0; j <= qt; ++j) {
        const float* kb = qkv + ((size_t)(b * Tt + j * 64 + tid)) * (3 * Cc) + Cc + h * Dd;
        const float* vb = kb + Cc;
        __syncthreads();
        #pragma unroll
        for (int i = 0; i < 16; ++i) {
            *(float4*)&Ks[tid][i * 4] = *(const float4*)&kb[i * 4];
            *(float4*)&Vs[tid][i * 4] = *(const float4*)&vb[i * 4];
        }
        __syncthreads();
        int klim = (j < qt) ? 64 : (tid + 1);
        for (int k = 0; k < klim; ++k) {
            float s = 0.f;
            #pragma unroll
            for (int i = 0; i < 16; ++i) {
                float4 kv = *(const float4*)&Ks[k][i * 4];
                s += q4[i].x * kv.x + q4[i].y * kv.y + q4[i].z * kv.z + q4[i].w * kv.w;
            }
            s *= 0.125f;  // 1/sqrt(64)
            if (s <= m) {
                float p = __expf(s - m);
                l += p;
                #pragma unroll
                for (int i = 0; i < 16; ++i) {
                    float4 vv = *(const float4*)&Vs[k][i * 4];
                    a4[i].x += p * vv.x; a4[i].y += p * vv.y;
                    a4[i].z += p * vv.z; a4[i].w += p * vv.w;
                }
            } else {
                float f = __expf(m - s);
                m = s;
                l = l * f + 1.f;
                #pragma unroll
                for (int i = 0; i < 16; ++i) {
                    float4 vv = *(const float4*)&Vs[k][i * 4];
                    a4[i].x = a4[i].x * f + vv.x; a4[i].y = a4[i].y * f + vv.y;
                    a4[i].z = a4[i].z * f + vv.z; a4[i].w = a4[i].w * f + vv.w;
                }
            }
        }
    }
    float inv = 1.f / l;
    float* ob = out + ((size_t)(b * Tt + qg)) * Cc + h * Dd;
    #pragma unroll
    for (int i = 0; i < 16; ++i) {
        float4 o = make_float4(a4[i].x * inv, a4[i].y * inv, a4[i].z * inv, a4[i].w * inv);
        *(float4*)&ob[i * 4] = o;
    }
}

// ---------------------------------------------------------------------------
// Launch
// ---------------------------------------------------------------------------
extern "C" void kernel_launch(void* const* d_in, const int* in_sizes, int n_in,
                              void* d_out, int out_size, void* d_ws, size_t ws_size,
                              hipStream_t stream) {
    const float* x      = (const float*)d_in[0];
    // d_in[1] = attention_mask (all ones; unused by the reference math)
    const float* w_qkv  = (const float*)d_in[2];
    const float* b_qkv  = (const float*)d_in[3];
    const float* w_o    = (const float*)d_in[4];
    const float* b_o    = (const float*)d_in[5];
    const float* rms_w  = (const float*)d_in[6];
    float* out = (float*)d_out;

    char* ws = (char*)d_ws;
    float* xn   = (float*)ws;                                   // 16 MB (reused as attn out)
    float* qkv  = (float*)(ws + (size_t)(16 << 20));            // 48 MB
    float* cosT = (float*)(ws + (size_t)(64 << 20));            // 256 KB
    float* sinT = (float*)(ws + (size_t)(64 << 20) + (1 << 18));// 256 KB

    rope_tables_k<<<dim3(Tt / 2), dim3(64), 0, stream>>>(cosT, sinT);
    rmsnorm_k<<<dim3(M_ROWS), dim3(256), 0, stream>>>(x, rms_w, xn);
    gemm_bias_k<<<dim3(3 * Cc / 64, M_ROWS / 64), dim3(256), 0, stream>>>(
        xn, w_qkv, b_qkv, qkv, M_ROWS, 3 * Cc, Cc);
    rope_apply_k<<<dim3((Bb * Tt * 2 * Hh * 32) / 256), dim3(256), 0, stream>>>(
        qkv, cosT, sinT);
    attn_k<<<dim3(Tt / 64, Hh, Bb), dim3(64), 0, stream>>>(qkv, xn);
    gemm_bias_k<<<dim3(Cc / 64, M_ROWS / 64), dim3(256), 0, stream>>>(
        xn, w_o, b_o, out, M_ROWS, Cc, Cc);
}

// Round 5
// 585.574 us; speedup vs baseline: 3.3515x; 3.3515x over previous
//
#include <hip/hip_runtime.h>
#include <math.h>

// Problem constants: B=2, T=2048, C=1024, H=16, D=64
constexpr int Bb = 2;
constexpr int Tt = 2048;
constexpr int Cc = 1024;
constexpr int Hh = 16;
constexpr int Dd = 64;
constexpr int M_ROWS = Bb * Tt;          // 4096
constexpr float EPSV = 1e-5f;

typedef __attribute__((ext_vector_type(4))) float f32x4;
typedef __attribute__((ext_vector_type(8))) __bf16 bf16x8;
using u16 = unsigned short;

union Frag8 {
    u16 u[8];
    unsigned int ui[4];
    bf16x8 b;
};

// fp32 -> bf16 round-to-nearest-even
__device__ __forceinline__ u16 f2bf(float f) {
    union { float f; unsigned int u; } c;
    c.f = f;
    unsigned int r = (c.u + 0x7fffu + ((c.u >> 16) & 1u)) >> 16;
    return (u16)r;
}

// ---------------------------------------------------------------------------
// RoPE tables: cos/sin [T][32]
// ---------------------------------------------------------------------------
__global__ __launch_bounds__(64) void rope_tables_k(float* __restrict__ cosT,
                                                    float* __restrict__ sinT) {
    int tid = threadIdx.x;
    int t = blockIdx.x * 2 + (tid >> 5);
    int j = tid & 31;
    float inv = exp2f(-(float)j * (log2f(10000.0f) / 32.0f));
    float a = (float)t * inv;
    cosT[t * 32 + j] = cosf(a);
    sinT[t * 32 + j] = sinf(a);
}

// ---------------------------------------------------------------------------
// RMSNorm: one block per row of C=1024; 256 threads x float4
// ---------------------------------------------------------------------------
__global__ __launch_bounds__(256) void rmsnorm_k(const float* __restrict__ x,
                                                 const float* __restrict__ w,
                                                 float* __restrict__ xn) {
    int row = blockIdx.x;
    int tid = threadIdx.x;
    const float* xr = x + (size_t)row * Cc;
    float4 v = *(const float4*)&xr[tid * 4];
    float ss = v.x * v.x + v.y * v.y + v.z * v.z + v.w * v.w;
    #pragma unroll
    for (int off = 32; off > 0; off >>= 1) ss += __shfl_down(ss, off);
    __shared__ float ws_[4];
    if ((tid & 63) == 0) ws_[tid >> 6] = ss;
    __syncthreads();
    float tot = ws_[0] + ws_[1] + ws_[2] + ws_[3];
    float r = rsqrtf(tot * (1.0f / (float)Cc) + EPSV);
    float4 wv = *(const float4*)&w[tid * 4];
    float4 o;
    o.x = v.x * r * wv.x;
    o.y = v.y * r * wv.y;
    o.z = v.z * r * wv.z;
    o.w = v.w * r * wv.w;
    *(float4*)&xn[(size_t)row * Cc + tid * 4] = o;
}

// ---------------------------------------------------------------------------
// Tiled fp32 GEMM: O[M][N] = A[M][K] * W[N][K]^T + bias[N]  (unchanged)
// ---------------------------------------------------------------------------
__global__ __launch_bounds__(256) void gemm_bias_k(const float* __restrict__ A,
                                                   const float* __restrict__ W,
                                                   const float* __restrict__ bias,
                                                   float* __restrict__ O,
                                                   int M, int N, int K) {
    __shared__ float As[16][68];
    __shared__ float Bs[16][68];
    int tid = threadIdx.x;
    int m0 = blockIdx.y * 64;
    int n0 = blockIdx.x * 64;
    int lr = tid >> 2;
    int lc = (tid & 3) * 4;
    int tx = (tid & 15) * 4;
    int ty = (tid >> 4) * 4;
    float acc[4][4] = {};
    for (int k0 = 0; k0 < K; k0 += 16) {
        float4 av = *(const float4*)&A[(size_t)(m0 + lr) * K + k0 + lc];
        float4 bv = *(const float4*)&W[(size_t)(n0 + lr) * K + k0 + lc];
        __syncthreads();
        As[lc + 0][lr] = av.x; As[lc + 1][lr] = av.y;
        As[lc + 2][lr] = av.z; As[lc + 3][lr] = av.w;
        Bs[lc + 0][lr] = bv.x; Bs[lc + 1][lr] = bv.y;
        Bs[lc + 2][lr] = bv.z; Bs[lc + 3][lr] = bv.w;
        __syncthreads();
        #pragma unroll
        for (int k = 0; k < 16; ++k) {
            float4 a4 = *(const float4*)&As[k][ty];
            float4 b4 = *(const float4*)&Bs[k][tx];
            float ar[4] = {a4.x, a4.y, a4.z, a4.w};
            float br[4] = {b4.x, b4.y, b4.z, b4.w};
            #pragma unroll
            for (int i = 0; i < 4; ++i)
                #pragma unroll
                for (int j = 0; j < 4; ++j)
                    acc[i][j] += ar[i] * br[j];
        }
    }
    float4 bvv = *(const float4*)&bias[n0 + tx];
    float bb[4] = {bvv.x, bvv.y, bvv.z, bvv.w};
    #pragma unroll
    for (int i = 0; i < 4; ++i) {
        float4 o;
        o.x = acc[i][0] + bb[0];
        o.y = acc[i][1] + bb[1];
        o.z = acc[i][2] + bb[2];
        o.w = acc[i][3] + bb[3];
        *(float4*)&O[(size_t)(m0 + ty + i) * N + n0 + tx] = o;
    }
}

// ---------------------------------------------------------------------------
// RoPE in-place on q and k planes of qkv [B,T,3,H,D]  (unchanged)
// ---------------------------------------------------------------------------
__global__ __launch_bounds__(256) void rope_apply_k(float* __restrict__ qkv,
                                                    const float* __restrict__ cosT,
                                                    const float* __restrict__ sinT) {
    int idx = blockIdx.x * 256 + threadIdx.x;
    int d = idx & 31;  int w = idx >> 5;
    int h = w & 15;    w >>= 4;
    int s = w & 1;     w >>= 1;
    int t = w & 2047;  int b = w >> 11;
    float* p = qkv + ((size_t)(b * Tt + t)) * (3 * Cc) + s * Cc + h * Dd + d;
    float c  = cosT[t * 32 + d];
    float sn = sinT[t * 32 + d];
    float x0 = p[0];
    float x1 = p[32];
    p[0]  = x0 * c - x1 * sn;
    p[32] = x1 * c + x0 * sn;
}

// ---------------------------------------------------------------------------
// MFMA flash attention (bf16 compute, fp32 accumulate).
// Block = 256 threads (4 waves), one (b,h), 64 q rows (wave w owns 16 rows).
// Swapped QK^T: S^T = mfma(K_frag, Q_frag) -> lane owns q = lane&15.
// K in LDS [64key][64d] bf16, XOR-swizzled; V in LDS transposed [64d][64key];
// P transposed through per-wave LDS buffer for the PV A-fragment.
// ---------------------------------------------------------------------------
__global__ __launch_bounds__(256) void attn_mfma_k(const float* __restrict__ qkv,
                                                   float* __restrict__ out) {
    const int qt = (gridDim.x - 1) - blockIdx.x;   // heavy tiles dispatch first
    const int h = blockIdx.y, b = blockIdx.z;
    const int t = threadIdx.x;
    const int w = t >> 6;       // wave 0..3
    const int l = t & 63;       // lane
    const int q15 = l & 15;
    const int g2 = l >> 4;      // 0..3
    const int swp = (q15 & 7) << 4;

    __shared__ __align__(16) char lds[24576];
    char* Ks = lds;                       // [64][128B] (64 bf16/row), swizzled
    char* VT = lds + 8192;                // [64 d][128B] keys, swizzled
    char* Pw = lds + 16384 + w * 2048;    // per-wave [16 q][128B] keys, swizzled

    const float* base = qkv + (size_t)b * Tt * 3072;

    // --- Q fragments (B operand of swapped QK^T), 1/sqrt(D) folded in ---
    const int qrow = qt * 64 + w * 16 + q15;
    Frag8 qf[2];
    {
        const float* qp = base + (size_t)qrow * 3072 + h * 64;
        #pragma unroll
        for (int kk = 0; kk < 2; ++kk) {
            int d0 = kk * 32 + g2 * 8;
            float4 a = *(const float4*)&qp[d0];
            float4 c = *(const float4*)&qp[d0 + 4];
            qf[kk].u[0] = f2bf(a.x * 0.125f);
            qf[kk].u[1] = f2bf(a.y * 0.125f);
            qf[kk].u[2] = f2bf(a.z * 0.125f);
            qf[kk].u[3] = f2bf(a.w * 0.125f);
            qf[kk].u[4] = f2bf(c.x * 0.125f);
            qf[kk].u[5] = f2bf(c.y * 0.125f);
            qf[kk].u[6] = f2bf(c.z * 0.125f);
            qf[kk].u[7] = f2bf(c.w * 0.125f);
        }
    }

    f32x4 acco[4];
    #pragma unroll
    for (int dg = 0; dg < 4; ++dg) acco[dg] = (f32x4){0.f, 0.f, 0.f, 0.f};
    float m_run = -INFINITY, l_run = 0.f;

    for (int kt = 0; kt <= qt; ++kt) {
        __syncthreads();   // previous tile's LDS reads done before overwrite
        // ---- stage K tile: [64 key][64 d] bf16, swizzled ----
        {
            int key = t >> 2;
            int dc = (t & 3) * 16;
            const float* kp = base + (size_t)(kt * 64 + key) * 3072 + 1024 + h * 64 + dc;
            int sw = (key & 7) << 4;
            #pragma unroll
            for (int j = 0; j < 4; ++j) {
                float4 v = *(const float4*)&kp[4 * j];
                uint2 pk;
                pk.x = (unsigned int)f2bf(v.x) | ((unsigned int)f2bf(v.y) << 16);
                pk.y = (unsigned int)f2bf(v.z) | ((unsigned int)f2bf(v.w) << 16);
                *(uint2*)&Ks[key * 128 + (((dc + 4 * j) * 2) ^ sw)] = pk;
            }
        }
        // ---- stage V tile transposed: VT[d][key] bf16, swizzled ----
        {
            int d = t & 63;
            int kg = t >> 6;   // keys 16kg .. 16kg+15
            const float* vp = base + (size_t)(kt * 64 + 16 * kg) * 3072 + 2048 + h * 64 + d;
            int sw = (d & 7) << 4;
            u16 tmp[16];
            #pragma unroll
            for (int j = 0; j < 16; ++j) tmp[j] = f2bf(vp[(size_t)j * 3072]);
            #pragma unroll
            for (int jq = 0; jq < 4; ++jq) {
                uint2 pk;
                pk.x = (unsigned int)tmp[4 * jq] | ((unsigned int)tmp[4 * jq + 1] << 16);
                pk.y = (unsigned int)tmp[4 * jq + 2] | ((unsigned int)tmp[4 * jq + 3] << 16);
                *(uint2*)&VT[d * 128 + (((16 * kg + 4 * jq) * 2) ^ sw)] = pk;
            }
        }
        __syncthreads();

        // ---- QK^T (swapped): S^T[key][q], key=(g*16 + g2*4 + r), q=q15 ----
        f32x4 sacc[4];
        #pragma unroll
        for (int g = 0; g < 4; ++g) {
            sacc[g] = (f32x4){0.f, 0.f, 0.f, 0.f};
            int krow = g * 16 + q15;
            #pragma unroll
            for (int kk = 0; kk < 2; ++kk) {
                Frag8 kf = *(Frag8*)&Ks[krow * 128 + ((64 * kk + 16 * g2) ^ swp)];
                sacc[g] = __builtin_amdgcn_mfma_f32_16x16x32_bf16(kf.b, qf[kk].b, sacc[g], 0, 0, 0);
            }
        }
        // causal mask (diagonal tile only)
        if (kt == qt) {
            #pragma unroll
            for (int g = 0; g < 4; ++g)
                #pragma unroll
                for (int r = 0; r < 4; ++r)
                    if (g * 16 + g2 * 4 + r > w * 16 + q15) sacc[g][r] = -1e30f;
        }

        // ---- online softmax (q = q15; 4 lanes share a q via xor 16/32) ----
        float mt = -INFINITY;
        #pragma unroll
        for (int g = 0; g < 4; ++g)
            #pragma unroll
            for (int r = 0; r < 4; ++r) mt = fmaxf(mt, sacc[g][r]);
        mt = fmaxf(mt, __shfl_xor(mt, 16));
        mt = fmaxf(mt, __shfl_xor(mt, 32));
        float mnew = fmaxf(m_run, mt);
        float fsc = __expf(m_run - mnew);
        m_run = mnew;
        float psum = 0.f;
        #pragma unroll
        for (int g = 0; g < 4; ++g) {
            float p0 = __expf(sacc[g][0] - mnew);
            float p1 = __expf(sacc[g][1] - mnew);
            float p2 = __expf(sacc[g][2] - mnew);
            float p3 = __expf(sacc[g][3] - mnew);
            psum += (p0 + p1) + (p2 + p3);
            uint2 pk;
            pk.x = (unsigned int)f2bf(p0) | ((unsigned int)f2bf(p1) << 16);
            pk.y = (unsigned int)f2bf(p2) | ((unsigned int)f2bf(p3) << 16);
            *(uint2*)&Pw[q15 * 128 + ((32 * g + 8 * g2) ^ swp)] = pk;
        }
        psum += __shfl_xor(psum, 16);
        psum += __shfl_xor(psum, 32);
        l_run = l_run * fsc + psum;

        // rescale O accumulator: rows are q = g2*4+r -> fetch their f
        float fr[4];
        #pragma unroll
        for (int r = 0; r < 4; ++r) fr[r] = __shfl(fsc, g2 * 4 + r);
        #pragma unroll
        for (int dg = 0; dg < 4; ++dg)
            #pragma unroll
            for (int r = 0; r < 4; ++r) acco[dg][r] *= fr[r];

        // ---- PV: O[q][d] += P[q][keys] * V[keys][d] ----
        Frag8 pa[2];
        #pragma unroll
        for (int kk = 0; kk < 2; ++kk)
            pa[kk] = *(Frag8*)&Pw[q15 * 128 + ((64 * kk + 16 * g2) ^ swp)];
        #pragma unroll
        for (int dg = 0; dg < 4; ++dg) {
            int vrow = dg * 16 + q15;
            #pragma unroll
            for (int kk = 0; kk < 2; ++kk) {
                Frag8 vf = *(Frag8*)&VT[vrow * 128 + ((64 * kk + 16 * g2) ^ swp)];
                acco[dg] = __builtin_amdgcn_mfma_f32_16x16x32_bf16(pa[kk].b, vf.b, acco[dg], 0, 0, 0);
            }
        }
    }

    // ---- epilogue: O rows are q = g2*4+r; divide by their l ----
    float lr[4];
    #pragma unroll
    for (int r = 0; r < 4; ++r) lr[r] = 1.f / __shfl(l_run, g2 * 4 + r);
    const int qbase = qt * 64 + w * 16;
    #pragma unroll
    for (int dg = 0; dg < 4; ++dg)
        #pragma unroll
        for (int r = 0; r < 4; ++r)
            out[((size_t)(b * Tt + qbase + g2 * 4 + r)) * Cc + h * 64 + dg * 16 + q15] =
                acco[dg][r] * lr[r];
}

// ---------------------------------------------------------------------------
// Launch
// ---------------------------------------------------------------------------
extern "C" void kernel_launch(void* const* d_in, const int* in_sizes, int n_in,
                              void* d_out, int out_size, void* d_ws, size_t ws_size,
                              hipStream_t stream) {
    const float* x      = (const float*)d_in[0];
    const float* w_qkv  = (const float*)d_in[2];
    const float* b_qkv  = (const float*)d_in[3];
    const float* w_o    = (const float*)d_in[4];
    const float* b_o    = (const float*)d_in[5];
    const float* rms_w  = (const float*)d_in[6];
    float* out = (float*)d_out;

    char* ws = (char*)d_ws;
    float* xn   = (float*)ws;                                    // 16 MB (reused as attn out)
    float* qkv  = (float*)(ws + (size_t)(16 << 20));             // 48 MB
    float* cosT = (float*)(ws + (size_t)(64 << 20));             // 256 KB
    float* sinT = (float*)(ws + (size_t)(64 << 20) + (1 << 18)); // 256 KB

    rope_tables_k<<<dim3(Tt / 2), dim3(64), 0, stream>>>(cosT, sinT);
    rmsnorm_k<<<dim3(M_ROWS), dim3(256), 0, stream>>>(x, rms_w, xn);
    gemm_bias_k<<<dim3(3 * Cc / 64, M_ROWS / 64), dim3(256), 0, stream>>>(
        xn, w_qkv, b_qkv, qkv, M_ROWS, 3 * Cc, Cc);
    rope_apply_k<<<dim3((Bb * Tt * 2 * Hh * 32) / 256), dim3(256), 0, stream>>>(
        qkv, cosT, sinT);
    attn_mfma_k<<<dim3(Tt / 64, Hh, Bb), dim3(256), 0, stream>>>(qkv, xn);
    gemm_bias_k<<<dim3(Cc / 64, M_ROWS / 64), dim3(256), 0, stream>>>(
        xn, w_o, b_o, out, M_ROWS, Cc, Cc);
}

// Round 7
// 198.834 us; speedup vs baseline: 9.8704x; 2.9450x over previous
//
#include <hip/hip_runtime.h>
#include <math.h>

// Problem constants: B=2, T=2048, C=1024, H=16, D=64
constexpr int Bb = 2;
constexpr int Tt = 2048;
constexpr int Cc = 1024;
constexpr int Hh = 16;
constexpr int M_ROWS = Bb * Tt;          // 4096
constexpr float EPSV = 1e-5f;

typedef __attribute__((ext_vector_type(4))) float f32x4;
typedef __attribute__((ext_vector_type(8))) __bf16 bf16x8;
using u16 = unsigned short;

union Frag8 {
    u16 u[8];
    unsigned int ui[4];
    bf16x8 b;
};

// fp32 -> bf16 round-to-nearest-even
__device__ __forceinline__ u16 f2bf(float f) {
    union { float f; unsigned int u; } c;
    c.f = f;
    unsigned int r = (c.u + 0x7fffu + ((c.u >> 16) & 1u)) >> 16;
    return (u16)r;
}

// async global->LDS, 16 B per lane; LDS dest = wave-uniform base + lane*16
__device__ __forceinline__ void gload_lds16(const void* g, void* l) {
    __builtin_amdgcn_global_load_lds(
        (__attribute__((address_space(1))) void*)const_cast<void*>(g),
        (__attribute__((address_space(3))) void*)l, 16, 0, 0);
}

// ---------------------------------------------------------------------------
// RoPE tables: cos/sin [T][32]
// ---------------------------------------------------------------------------
__global__ __launch_bounds__(64) void rope_tables_k(float* __restrict__ cosT,
                                                    float* __restrict__ sinT) {
    int tid = threadIdx.x;
    int t = blockIdx.x * 2 + (tid >> 5);
    int j = tid & 31;
    float inv = exp2f(-(float)j * (log2f(10000.0f) / 32.0f));
    float a = (float)t * inv;
    cosT[t * 32 + j] = cosf(a);
    sinT[t * 32 + j] = sinf(a);
}

// ---------------------------------------------------------------------------
// fp32 -> bf16 array convert (for weights), 4 elems/thread
// ---------------------------------------------------------------------------
__global__ __launch_bounds__(256) void f2bf_arr_k(const float* __restrict__ in,
                                                  u16* __restrict__ out) {
    int i = (blockIdx.x * 256 + threadIdx.x) * 4;
    float4 v = *(const float4*)&in[i];
    ushort4 o;
    o.x = f2bf(v.x); o.y = f2bf(v.y); o.z = f2bf(v.z); o.w = f2bf(v.w);
    *(ushort4*)&out[i] = o;
}

// ---------------------------------------------------------------------------
// RMSNorm: one block per row of C=1024; 256 threads x float4 -> bf16 out
// ---------------------------------------------------------------------------
__global__ __launch_bounds__(256) void rmsnorm_k(const float* __restrict__ x,
                                                 const float* __restrict__ w,
                                                 u16* __restrict__ xn) {
    int row = blockIdx.x;
    int tid = threadIdx.x;
    const float* xr = x + (size_t)row * Cc;
    float4 v = *(const float4*)&xr[tid * 4];
    float ss = v.x * v.x + v.y * v.y + v.z * v.z + v.w * v.w;
    #pragma unroll
    for (int off = 32; off > 0; off >>= 1) ss += __shfl_down(ss, off);
    __shared__ float ws_[4];
    if ((tid & 63) == 0) ws_[tid >> 6] = ss;
    __syncthreads();
    float tot = ws_[0] + ws_[1] + ws_[2] + ws_[3];
    float r = rsqrtf(tot * (1.0f / (float)Cc) + EPSV);
    float4 wv = *(const float4*)&w[tid * 4];
    ushort4 o;
    o.x = f2bf(v.x * r * wv.x);
    o.y = f2bf(v.y * r * wv.y);
    o.z = f2bf(v.z * r * wv.z);
    o.w = f2bf(v.w * r * wv.w);
    *(ushort4*)&xn[(size_t)row * Cc + tid * 4] = o;
}

// ---------------------------------------------------------------------------
// bf16 MFMA GEMM: O[M][N] = A[M][K]_bf16 * W[N][K]_bf16^T + bias[N], O fp32.
// 128x128 tile, BK=64, 256 threads = 4 waves (2x2), 64x64 per wave.
// Staging: global_load_lds dwordx4, linear LDS [128 rows][64 bf16], with
// chunk-XOR swizzle p = c ^ (row&7) applied on the GLOBAL source address and
// identically on the ds_read_b128 fragment reads (involution, rule #21).
// ---------------------------------------------------------------------------
__global__ __launch_bounds__(256) void gemm_mfma_k(const u16* __restrict__ A,
                                                   const u16* __restrict__ W,
                                                   const float* __restrict__ bias,
                                                   float* __restrict__ O,
                                                   int M, int N, int K) {
    __shared__ __align__(16) u16 As[128 * 64];   // 16 KB
    __shared__ __align__(16) u16 Bs[128 * 64];   // 16 KB

    const int tid = threadIdx.x;
    const int w = tid >> 6;          // wave 0..3
    const int l = tid & 63;          // lane
    const int wr = w >> 1;           // wave row (0..1)
    const int wc = w & 1;            // wave col (0..1)
    const int q = l & 15;            // frag row-within-16
    const int g = l >> 4;            // frag k-group (0..3)

    const int m0 = blockIdx.y * 128;
    const int n0 = blockIdx.x * 128;

    // staging indices (per wave-issue block of 8 rows)
    const int srow_in = l >> 3;      // 0..7 row within 8-row block
    const int p_chunk = l & 7;       // physical 16B chunk within 128B row

    f32x4 acc[4][4];
    #pragma unroll
    for (int i = 0; i < 4; ++i)
        #pragma unroll
        for (int j = 0; j < 4; ++j)
            acc[i][j] = (f32x4){0.f, 0.f, 0.f, 0.f};

    const int nkt = K >> 6;          // BK=64
    for (int kt = 0; kt < nkt; ++kt) {
        const int k0 = kt << 6;
        __syncthreads();  // previous iter's ds_reads done before overwrite
        // ---- stage A and B tiles: 4 issues per wave per tile ----
        #pragma unroll
        for (int s = 0; s < 4; ++s) {
            int blk = s * 4 + w;                 // 8-row block 0..15
            int r = blk * 8 + srow_in;           // row 0..127
            int c = p_chunk ^ (r & 7);           // logical chunk for this slot
            gload_lds16(A + (size_t)(m0 + r) * K + k0 + c * 8, &As[blk * 512]);
            gload_lds16(W + (size_t)(n0 + r) * K + k0 + c * 8, &Bs[blk * 512]);
        }
        __syncthreads();  // compiler drains vmcnt before the barrier

        // ---- compute: 2 k-halves x 16 mfma ----
        #pragma unroll
        for (int kk = 0; kk < 2; ++kk) {
            Frag8 af[4], bf[4];
            const int ca = kk * 4 + g;           // logical chunk (8 bf16)
            #pragma unroll
            for (int i = 0; i < 4; ++i) {
                int ra = wr * 64 + i * 16 + q;
                af[i] = *(const Frag8*)&As[ra * 64 + ((ca ^ (ra & 7)) * 8)];
                int rb = wc * 64 + i * 16 + q;
                bf[i] = *(const Frag8*)&Bs[rb * 64 + ((ca ^ (rb & 7)) * 8)];
            }
            #pragma unroll
            for (int i = 0; i < 4; ++i)
                #pragma unroll
                for (int j = 0; j < 4; ++j)
                    acc[i][j] = __builtin_amdgcn_mfma_f32_16x16x32_bf16(
                        af[i].b, bf[j].b, acc[i][j], 0, 0, 0);
        }
    }

    // ---- epilogue: bias + store (D layout: col=lane&15, row=(lane>>4)*4+r) ----
    #pragma unroll
    for (int i = 0; i < 4; ++i) {
        int row = m0 + wr * 64 + i * 16 + g * 4;
        #pragma unroll
        for (int j = 0; j < 4; ++j) {
            int col = n0 + wc * 64 + j * 16 + q;
            float bb = bias[col];
            #pragma unroll
            for (int r2 = 0; r2 < 4; ++r2)
                O[(size_t)(row + r2) * N + col] = acc[i][j][r2] + bb;
        }
    }
}

// ---------------------------------------------------------------------------
// RoPE in-place on q and k planes of qkv [B,T,3,H,D]  (unchanged)
// ---------------------------------------------------------------------------
__global__ __launch_bounds__(256) void rope_apply_k(float* __restrict__ qkv,
                                                    const float* __restrict__ cosT,
                                                    const float* __restrict__ sinT) {
    int idx = blockIdx.x * 256 + threadIdx.x;
    int d = idx & 31;  int w = idx >> 5;
    int h = w & 15;    w >>= 4;
    int s = w & 1;     w >>= 1;
    int t = w & 2047;  int b = w >> 11;
    float* p = qkv + ((size_t)(b * Tt + t)) * (3 * Cc) + s * Cc + h * 64 + d;
    float c  = cosT[t * 32 + d];
    float sn = sinT[t * 32 + d];
    float x0 = p[0];
    float x1 = p[32];
    p[0]  = x0 * c - x1 * sn;
    p[32] = x1 * c + x0 * sn;
}

// ---------------------------------------------------------------------------
// MFMA flash attention (bf16 compute, fp32 accumulate) -> bf16 out.
// Unchanged from Round 5 except the epilogue stores bf16.
// ---------------------------------------------------------------------------
__global__ __launch_bounds__(256) void attn_mfma_k(const float* __restrict__ qkv,
                                                   u16* __restrict__ out) {
    const int qt = (gridDim.x - 1) - blockIdx.x;   // heavy tiles dispatch first
    const int h = blockIdx.y, b = blockIdx.z;
    const int t = threadIdx.x;
    const int w = t >> 6;       // wave 0..3
    const int l = t & 63;       // lane
    const int q15 = l & 15;
    const int g2 = l >> 4;      // 0..3
    const int swp = (q15 & 7) << 4;

    __shared__ __align__(16) char lds[24576];
    char* Ks = lds;                       // [64][128B] (64 bf16/row), swizzled
    char* VT = lds + 8192;                // [64 d][128B] keys, swizzled
    char* Pw = lds + 16384 + w * 2048;    // per-wave [16 q][128B] keys, swizzled

    const float* base = qkv + (size_t)b * Tt * 3072;

    // --- Q fragments (B operand of swapped QK^T), 1/sqrt(D) folded in ---
    const int qrow = qt * 64 + w * 16 + q15;
    Frag8 qf[2];
    {
        const float* qp = base + (size_t)qrow * 3072 + h * 64;
        #pragma unroll
        for (int kk = 0; kk < 2; ++kk) {
            int d0 = kk * 32 + g2 * 8;
            float4 a = *(const float4*)&qp[d0];
            float4 c = *(const float4*)&qp[d0 + 4];
            qf[kk].u[0] = f2bf(a.x * 0.125f);
            qf[kk].u[1] = f2bf(a.y * 0.125f);
            qf[kk].u[2] = f2bf(a.z * 0.125f);
            qf[kk].u[3] = f2bf(a.w * 0.125f);
            qf[kk].u[4] = f2bf(c.x * 0.125f);
            qf[kk].u[5] = f2bf(c.y * 0.125f);
            qf[kk].u[6] = f2bf(c.z * 0.125f);
            qf[kk].u[7] = f2bf(c.w * 0.125f);
        }
    }

    f32x4 acco[4];
    #pragma unroll
    for (int dg = 0; dg < 4; ++dg) acco[dg] = (f32x4){0.f, 0.f, 0.f, 0.f};
    float m_run = -INFINITY, l_run = 0.f;

    for (int kt = 0; kt <= qt; ++kt) {
        __syncthreads();
        // ---- stage K tile: [64 key][64 d] bf16, swizzled ----
        {
            int key = t >> 2;
            int dc = (t & 3) * 16;
            const float* kp = base + (size_t)(kt * 64 + key) * 3072 + 1024 + h * 64 + dc;
            int sw = (key & 7) << 4;
            #pragma unroll
            for (int j = 0; j < 4; ++j) {
                float4 v = *(const float4*)&kp[4 * j];
                uint2 pk;
                pk.x = (unsigned int)f2bf(v.x) | ((unsigned int)f2bf(v.y) << 16);
                pk.y = (unsigned int)f2bf(v.z) | ((unsigned int)f2bf(v.w) << 16);
                *(uint2*)&Ks[key * 128 + (((dc + 4 * j) * 2) ^ sw)] = pk;
            }
        }
        // ---- stage V tile transposed: VT[d][key] bf16, swizzled ----
        {
            int d = t & 63;
            int kg = t >> 6;
            const float* vp = base + (size_t)(kt * 64 + 16 * kg) * 3072 + 2048 + h * 64 + d;
            int sw = (d & 7) << 4;
            u16 tmp[16];
            #pragma unroll
            for (int j = 0; j < 16; ++j) tmp[j] = f2bf(vp[(size_t)j * 3072]);
            #pragma unroll
            for (int jq = 0; jq < 4; ++jq) {
                uint2 pk;
                pk.x = (unsigned int)tmp[4 * jq] | ((unsigned int)tmp[4 * jq + 1] << 16);
                pk.y = (unsigned int)tmp[4 * jq + 2] | ((unsigned int)tmp[4 * jq + 3] << 16);
                *(uint2*)&VT[d * 128 + (((16 * kg + 4 * jq) * 2) ^ sw)] = pk;
            }
        }
        __syncthreads();

        // ---- QK^T (swapped): S^T[key][q] ----
        f32x4 sacc[4];
        #pragma unroll
        for (int g = 0; g < 4; ++g) {
            sacc[g] = (f32x4){0.f, 0.f, 0.f, 0.f};
            int krow = g * 16 + q15;
            #pragma unroll
            for (int kk = 0; kk < 2; ++kk) {
                Frag8 kf = *(Frag8*)&Ks[krow * 128 + ((64 * kk + 16 * g2) ^ swp)];
                sacc[g] = __builtin_amdgcn_mfma_f32_16x16x32_bf16(kf.b, qf[kk].b, sacc[g], 0, 0, 0);
            }
        }
        if (kt == qt) {
            #pragma unroll
            for (int g = 0; g < 4; ++g)
                #pragma unroll
                for (int r = 0; r < 4; ++r)
                    if (g * 16 + g2 * 4 + r > w * 16 + q15) sacc[g][r] = -1e30f;
        }

        // ---- online softmax ----
        float mt = -INFINITY;
        #pragma unroll
        for (int g = 0; g < 4; ++g)
            #pragma unroll
            for (int r = 0; r < 4; ++r) mt = fmaxf(mt, sacc[g][r]);
        mt = fmaxf(mt, __shfl_xor(mt, 16));
        mt = fmaxf(mt, __shfl_xor(mt, 32));
        float mnew = fmaxf(m_run, mt);
        float fsc = __expf(m_run - mnew);
        m_run = mnew;
        float psum = 0.f;
        #pragma unroll
        for (int g = 0; g < 4; ++g) {
            float p0 = __expf(sacc[g][0] - mnew);
            float p1 = __expf(sacc[g][1] - mnew);
            float p2 = __expf(sacc[g][2] - mnew);
            float p3 = __expf(sacc[g][3] - mnew);
            psum += (p0 + p1) + (p2 + p3);
            uint2 pk;
            pk.x = (unsigned int)f2bf(p0) | ((unsigned int)f2bf(p1) << 16);
            pk.y = (unsigned int)f2bf(p2) | ((unsigned int)f2bf(p3) << 16);
            *(uint2*)&Pw[q15 * 128 + ((32 * g + 8 * g2) ^ swp)] = pk;
        }
        psum += __shfl_xor(psum, 16);
        psum += __shfl_xor(psum, 32);
        l_run = l_run * fsc + psum;

        float fr[4];
        #pragma unroll
        for (int r = 0; r < 4; ++r) fr[r] = __shfl(fsc, g2 * 4 + r);
        #pragma unroll
        for (int dg = 0; dg < 4; ++dg)
            #pragma unroll
            for (int r = 0; r < 4; ++r) acco[dg][r] *= fr[r];

        // ---- PV ----
        Frag8 pa[2];
        #pragma unroll
        for (int kk = 0; kk < 2; ++kk)
            pa[kk] = *(Frag8*)&Pw[q15 * 128 + ((64 * kk + 16 * g2) ^ swp)];
        #pragma unroll
        for (int dg = 0; dg < 4; ++dg) {
            int vrow = dg * 16 + q15;
            #pragma unroll
            for (int kk = 0; kk < 2; ++kk) {
                Frag8 vf = *(Frag8*)&VT[vrow * 128 + ((64 * kk + 16 * g2) ^ swp)];
                acco[dg] = __builtin_amdgcn_mfma_f32_16x16x32_bf16(pa[kk].b, vf.b, acco[dg], 0, 0, 0);
            }
        }
    }

    // ---- epilogue: bf16 out ----
    float lr[4];
    #pragma unroll
    for (int r = 0; r < 4; ++r) lr[r] = 1.f / __shfl(l_run, g2 * 4 + r);
    const int qbase = qt * 64 + w * 16;
    #pragma unroll
    for (int dg = 0; dg < 4; ++dg)
        #pragma unroll
        for (int r = 0; r < 4; ++r)
            out[((size_t)(b * Tt + qbase + g2 * 4 + r)) * Cc + h * 64 + dg * 16 + q15] =
                f2bf(acco[dg][r] * lr[r]);
}

// ---------------------------------------------------------------------------
// Launch
// ---------------------------------------------------------------------------
extern "C" void kernel_launch(void* const* d_in, const int* in_sizes, int n_in,
                              void* d_out, int out_size, void* d_ws, size_t ws_size,
                              hipStream_t stream) {
    const float* x      = (const float*)d_in[0];
    const float* w_qkv  = (const float*)d_in[2];
    const float* b_qkv  = (const float*)d_in[3];
    const float* w_o    = (const float*)d_in[4];
    const float* b_o    = (const float*)d_in[5];
    const float* rms_w  = (const float*)d_in[6];
    float* out = (float*)d_out;

    char* ws = (char*)d_ws;
    u16*   xn_bf   = (u16*)ws;                                   // 8 MB (reused as attn out)
    u16*   wqkv_bf = (u16*)(ws + (size_t)(8 << 20));             // 6 MB
    u16*   wo_bf   = (u16*)(ws + (size_t)(14 << 20));            // 2 MB
    float* qkv     = (float*)(ws + (size_t)(16 << 20));          // 48 MB
    float* cosT    = (float*)(ws + (size_t)(64 << 20));          // 256 KB
    float* sinT    = (float*)(ws + (size_t)(64 << 20) + (1 << 18));
    u16*   attn_bf = xn_bf;   // xn dead after QKV GEMM

    rope_tables_k<<<dim3(Tt / 2), dim3(64), 0, stream>>>(cosT, sinT);
    f2bf_arr_k<<<dim3(3 * Cc * Cc / 1024), dim3(256), 0, stream>>>(w_qkv, wqkv_bf);
    f2bf_arr_k<<<dim3(Cc * Cc / 1024), dim3(256), 0, stream>>>(w_o, wo_bf);
    rmsnorm_k<<<dim3(M_ROWS), dim3(256), 0, stream>>>(x, rms_w, xn_bf);
    gemm_mfma_k<<<dim3(3 * Cc / 128, M_ROWS / 128), dim3(256), 0, stream>>>(
        xn_bf, wqkv_bf, b_qkv, qkv, M_ROWS, 3 * Cc, Cc);
    rope_apply_k<<<dim3((Bb * Tt * 2 * Hh * 32) / 256), dim3(256), 0, stream>>>(
        qkv, cosT, sinT);
    attn_mfma_k<<<dim3(Tt / 64, Hh, Bb), dim3(256), 0, stream>>>(qkv, attn_bf);
    gemm_mfma_k<<<dim3(Cc / 128, M_ROWS / 128), dim3(256), 0, stream>>>(
        attn_bf, wo_bf, b_o, out, M_ROWS, Cc, Cc);
}

// Round 8
// 180.037 us; speedup vs baseline: 10.9009x; 1.1044x over previous
//
#include <hip/hip_runtime.h>
#include <math.h>

// Problem constants: B=2, T=2048, C=1024, H=16, D=64
constexpr int Bb = 2;
constexpr int Tt = 2048;
constexpr int Cc = 1024;
constexpr int Hh = 16;
constexpr int M_ROWS = Bb * Tt;          // 4096
constexpr float EPSV = 1e-5f;

typedef __attribute__((ext_vector_type(4))) float f32x4;
typedef __attribute__((ext_vector_type(8))) __bf16 bf16x8;
using u16 = unsigned short;

union Frag8 {
    u16 u[8];
    unsigned int ui[4];
    uint4 v;
    bf16x8 b;
};

// fp32 -> bf16 round-to-nearest-even
__device__ __forceinline__ u16 f2bf(float f) {
    union { float f; unsigned int u; } c;
    c.f = f;
    unsigned int r = (c.u + 0x7fffu + ((c.u >> 16) & 1u)) >> 16;
    return (u16)r;
}
__device__ __forceinline__ float bf2f(u16 u) {
    union { unsigned int i; float f; } c;
    c.i = ((unsigned int)u) << 16;
    return c.f;
}

// async global->LDS, 16 B per lane; LDS dest = wave-uniform base + lane*16
__device__ __forceinline__ void gload_lds16(const void* g, void* l) {
    __builtin_amdgcn_global_load_lds(
        (__attribute__((address_space(1))) void*)const_cast<void*>(g),
        (__attribute__((address_space(3))) void*)l, 16, 0, 0);
}

// ---------------------------------------------------------------------------
// RoPE tables: cos/sin [T][32]
// ---------------------------------------------------------------------------
__global__ __launch_bounds__(64) void rope_tables_k(float* __restrict__ cosT,
                                                    float* __restrict__ sinT) {
    int tid = threadIdx.x;
    int t = blockIdx.x * 2 + (tid >> 5);
    int j = tid & 31;
    float inv = exp2f(-(float)j * (log2f(10000.0f) / 32.0f));
    float a = (float)t * inv;
    cosT[t * 32 + j] = cosf(a);
    sinT[t * 32 + j] = sinf(a);
}

// ---------------------------------------------------------------------------
// fp32 -> bf16 array convert (for weights), 4 elems/thread
// ---------------------------------------------------------------------------
__global__ __launch_bounds__(256) void f2bf_arr_k(const float* __restrict__ in,
                                                  u16* __restrict__ out) {
    int i = (blockIdx.x * 256 + threadIdx.x) * 4;
    float4 v = *(const float4*)&in[i];
    ushort4 o;
    o.x = f2bf(v.x); o.y = f2bf(v.y); o.z = f2bf(v.z); o.w = f2bf(v.w);
    *(ushort4*)&out[i] = o;
}

// ---------------------------------------------------------------------------
// RMSNorm: one block per row of C=1024; 256 threads x float4 -> bf16 out
// ---------------------------------------------------------------------------
__global__ __launch_bounds__(256) void rmsnorm_k(const float* __restrict__ x,
                                                 const float* __restrict__ w,
                                                 u16* __restrict__ xn) {
    int row = blockIdx.x;
    int tid = threadIdx.x;
    const float* xr = x + (size_t)row * Cc;
    float4 v = *(const float4*)&xr[tid * 4];
    float ss = v.x * v.x + v.y * v.y + v.z * v.z + v.w * v.w;
    #pragma unroll
    for (int off = 32; off > 0; off >>= 1) ss += __shfl_down(ss, off);
    __shared__ float ws_[4];
    if ((tid & 63) == 0) ws_[tid >> 6] = ss;
    __syncthreads();
    float tot = ws_[0] + ws_[1] + ws_[2] + ws_[3];
    float r = rsqrtf(tot * (1.0f / (float)Cc) + EPSV);
    float4 wv = *(const float4*)&w[tid * 4];
    ushort4 o;
    o.x = f2bf(v.x * r * wv.x);
    o.y = f2bf(v.y * r * wv.y);
    o.z = f2bf(v.z * r * wv.z);
    o.w = f2bf(v.w * r * wv.w);
    *(ushort4*)&xn[(size_t)row * Cc + tid * 4] = o;
}

// ---------------------------------------------------------------------------
// bf16 MFMA GEMM: O[M][N] = A[M][K]_bf16 * W[N][K]_bf16^T + bias[N].
// Output fp32 or bf16 (template). 128x128 tile, BK=64, 4 waves (2x2).
// global_load_lds staging with source-chunk XOR swizzle (rule #21).
// ---------------------------------------------------------------------------
template<bool BF16OUT>
__global__ __launch_bounds__(256) void gemm_mfma_k(const u16* __restrict__ A,
                                                   const u16* __restrict__ W,
                                                   const float* __restrict__ bias,
                                                   void* __restrict__ Ov,
                                                   int M, int N, int K) {
    __shared__ __align__(16) u16 As[128 * 64];   // 16 KB
    __shared__ __align__(16) u16 Bs[128 * 64];   // 16 KB

    const int tid = threadIdx.x;
    const int w = tid >> 6;
    const int l = tid & 63;
    const int wr = w >> 1;
    const int wc = w & 1;
    const int q = l & 15;
    const int g = l >> 4;

    const int m0 = blockIdx.y * 128;
    const int n0 = blockIdx.x * 128;

    const int srow_in = l >> 3;
    const int p_chunk = l & 7;

    f32x4 acc[4][4];
    #pragma unroll
    for (int i = 0; i < 4; ++i)
        #pragma unroll
        for (int j = 0; j < 4; ++j)
            acc[i][j] = (f32x4){0.f, 0.f, 0.f, 0.f};

    const int nkt = K >> 6;
    for (int kt = 0; kt < nkt; ++kt) {
        const int k0 = kt << 6;
        __syncthreads();
        #pragma unroll
        for (int s = 0; s < 4; ++s) {
            int blk = s * 4 + w;
            int r = blk * 8 + srow_in;
            int c = p_chunk ^ (r & 7);
            gload_lds16(A + (size_t)(m0 + r) * K + k0 + c * 8, &As[blk * 512]);
            gload_lds16(W + (size_t)(n0 + r) * K + k0 + c * 8, &Bs[blk * 512]);
        }
        __syncthreads();

        #pragma unroll
        for (int kk = 0; kk < 2; ++kk) {
            Frag8 af[4], bf[4];
            const int ca = kk * 4 + g;
            #pragma unroll
            for (int i = 0; i < 4; ++i) {
                int ra = wr * 64 + i * 16 + q;
                af[i] = *(const Frag8*)&As[ra * 64 + ((ca ^ (ra & 7)) * 8)];
                int rb = wc * 64 + i * 16 + q;
                bf[i] = *(const Frag8*)&Bs[rb * 64 + ((ca ^ (rb & 7)) * 8)];
            }
            #pragma unroll
            for (int i = 0; i < 4; ++i)
                #pragma unroll
                for (int j = 0; j < 4; ++j)
                    acc[i][j] = __builtin_amdgcn_mfma_f32_16x16x32_bf16(
                        af[i].b, bf[j].b, acc[i][j], 0, 0, 0);
        }
    }

    #pragma unroll
    for (int i = 0; i < 4; ++i) {
        int row = m0 + wr * 64 + i * 16 + g * 4;
        #pragma unroll
        for (int j = 0; j < 4; ++j) {
            int col = n0 + wc * 64 + j * 16 + q;
            float bb = bias[col];
            #pragma unroll
            for (int r2 = 0; r2 < 4; ++r2) {
                float val = acc[i][j][r2] + bb;
                if (BF16OUT)
                    ((u16*)Ov)[(size_t)(row + r2) * N + col] = f2bf(val);
                else
                    ((float*)Ov)[(size_t)(row + r2) * N + col] = val;
            }
        }
    }
}

// ---------------------------------------------------------------------------
// RoPE + repack: qkv_bf16 [b,t,3,h,64] -> Qb/Kb [b,h,t,64] bf16 (Q pre-scaled
// by 1/8), Vt [b,h,64,T] bf16 (transposed via LDS).
// Grid (T/64, H, B), 256 threads.
// ---------------------------------------------------------------------------
__global__ __launch_bounds__(256) void rope_pack_k(const u16* __restrict__ qkv,
                                                   const float* __restrict__ cosT,
                                                   const float* __restrict__ sinT,
                                                   u16* __restrict__ Qb,
                                                   u16* __restrict__ Kb,
                                                   u16* __restrict__ Vt) {
    const int t0 = blockIdx.x * 64;
    const int h = blockIdx.y, b = blockIdx.z;
    const int t = threadIdx.x;
    const int bh = b * Hh + h;
    __shared__ u16 Vs[64 * 64];

    // ---- stage V tile to LDS (row-major, bf16 passthrough) ----
    {
        int row = t >> 2, d16 = (t & 3) * 16;
        const u16* vp = qkv + (size_t)(b * Tt + t0 + row) * 3072 + 2048 + h * 64 + d16;
        *(uint4*)&Vs[row * 64 + d16]     = *(const uint4*)vp;
        *(uint4*)&Vs[row * 64 + d16 + 8] = *(const uint4*)(vp + 8);
    }

    // ---- RoPE on Q and K, head-major bf16 out ----
    {
        int row = t >> 2, d0 = (t & 3) * 8;
        size_t rb = (size_t)(b * Tt + t0 + row) * 3072 + h * 64;
        const u16* qp = qkv + rb;
        const u16* kp = qkv + rb + 1024;
        Frag8 qlo, qhi, klo, khi;
        qlo.v = *(const uint4*)&qp[d0];
        qhi.v = *(const uint4*)&qp[d0 + 32];
        klo.v = *(const uint4*)&kp[d0];
        khi.v = *(const uint4*)&kp[d0 + 32];
        const float* cp = &cosT[(t0 + row) * 32 + d0];
        const float* sp = &sinT[(t0 + row) * 32 + d0];
        float4 c0 = *(const float4*)cp, c1 = *(const float4*)(cp + 4);
        float4 s0 = *(const float4*)sp, s1 = *(const float4*)(sp + 4);
        float cc[8] = {c0.x, c0.y, c0.z, c0.w, c1.x, c1.y, c1.z, c1.w};
        float ss[8] = {s0.x, s0.y, s0.z, s0.w, s1.x, s1.y, s1.z, s1.w};
        Frag8 oql, oqh, okl, okh;
        #pragma unroll
        for (int i = 0; i < 8; ++i) {
            float ql = bf2f(qlo.u[i]), qh = bf2f(qhi.u[i]);
            float kl = bf2f(klo.u[i]), kh = bf2f(khi.u[i]);
            oql.u[i] = f2bf((ql * cc[i] - qh * ss[i]) * 0.125f);
            oqh.u[i] = f2bf((qh * cc[i] + ql * ss[i]) * 0.125f);
            okl.u[i] = f2bf(kl * cc[i] - kh * ss[i]);
            okh.u[i] = f2bf(kh * cc[i] + kl * ss[i]);
        }
        u16* qd = Qb + ((size_t)bh * Tt + t0 + row) * 64;
        u16* kd = Kb + ((size_t)bh * Tt + t0 + row) * 64;
        *(uint4*)&qd[d0]      = oql.v;
        *(uint4*)&qd[d0 + 32] = oqh.v;
        *(uint4*)&kd[d0]      = okl.v;
        *(uint4*)&kd[d0 + 32] = okh.v;
    }
    __syncthreads();

    // ---- V transpose out: Vt[bh][d][t] ----
    {
        int d = t >> 2, kq = (t & 3) * 16;
        Frag8 a, b2;
        #pragma unroll
        for (int j = 0; j < 8; ++j)  a.u[j]  = Vs[(kq + j) * 64 + d];
        #pragma unroll
        for (int j = 0; j < 8; ++j)  b2.u[j] = Vs[(kq + 8 + j) * 64 + d];
        u16* vd = Vt + ((size_t)bh * 64 + d) * Tt + t0 + kq;
        *(uint4*)&vd[0] = a.v;
        *(uint4*)&vd[8] = b2.v;
    }
}

// ---------------------------------------------------------------------------
// MFMA flash attention v2. Block = 4 waves, one (b,h), 128 q rows
// (2 q-sets of 64; wave w owns rows w*16.. in each set). KVBLK=64.
// K and V^T staged via global_load_lds (source-chunk XOR swizzle, linear LDS).
// Swapped QK^T; P transposed through per-wave LDS; PV from V^T tiles.
// ---------------------------------------------------------------------------
__global__ __launch_bounds__(256) void attn_mfma_k(const u16* __restrict__ Qb,
                                                   const u16* __restrict__ Kb,
                                                   const u16* __restrict__ Vt,
                                                   u16* __restrict__ out) {
    const int qt = (gridDim.x - 1) - blockIdx.x;   // heavy tiles first
    const int h = blockIdx.y, b = blockIdx.z;
    const int t = threadIdx.x;
    const int w = t >> 6;
    const int l = t & 63;
    const int q15 = l & 15;
    const int g2 = l >> 4;
    const int swp = (q15 & 7) << 4;
    const int bh = b * Hh + h;

    __shared__ __align__(16) u16 Ks[64 * 64];    // 8 KB, chunk-swizzled
    __shared__ __align__(16) u16 VTs[64 * 64];   // 8 KB, chunk-swizzled
    __shared__ __align__(16) char Pws[4 * 2048]; // per-wave P buffer
    char* Pw = Pws + w * 2048;

    // ---- Q fragments for both q-sets (scale pre-folded) ----
    Frag8 qf[2][2];
    #pragma unroll
    for (int s = 0; s < 2; ++s) {
        int qrow = qt * 128 + s * 64 + w * 16 + q15;
        const u16* qp = Qb + ((size_t)bh * Tt + qrow) * 64;
        qf[s][0] = *(const Frag8*)&qp[g2 * 8];
        qf[s][1] = *(const Frag8*)&qp[32 + g2 * 8];
    }

    f32x4 acco[2][4];
    #pragma unroll
    for (int s = 0; s < 2; ++s)
        #pragma unroll
        for (int dg = 0; dg < 4; ++dg) acco[s][dg] = (f32x4){0.f, 0.f, 0.f, 0.f};
    float m_run[2] = {-INFINITY, -INFINITY};
    float l_run[2] = {0.f, 0.f};

    const int srow = l >> 3;      // 0..7
    const int cph = l & 7;        // physical 16B chunk
    const u16* Kbase = Kb + (size_t)bh * Tt * 64;
    const u16* Vbase = Vt + (size_t)bh * 64 * Tt;

    const int jmax = 2 * qt + 1;
    for (int j = 0; j <= jmax; ++j) {
        __syncthreads();
        // ---- stage K tile [64key][64d] and V^T tile [64d][64key] ----
        #pragma unroll
        for (int iss = 0; iss < 2; ++iss) {
            int rr = w * 16 + iss * 8 + srow;
            int cl = cph ^ (rr & 7);
            gload_lds16(Kbase + (size_t)(j * 64 + rr) * 64 + cl * 8,
                        &Ks[(w * 16 + iss * 8) * 64]);
            gload_lds16(Vbase + (size_t)rr * Tt + j * 64 + cl * 8,
                        &VTs[(w * 16 + iss * 8) * 64]);
        }
        __syncthreads();

        #pragma unroll
        for (int s = 0; s < 2; ++s) {
            if (s == 0 && j == jmax) continue;   // fully-masked half-tile

            // ---- QK^T (swapped): S^T[key][q] ----
            f32x4 sacc[4];
            #pragma unroll
            for (int g = 0; g < 4; ++g) {
                sacc[g] = (f32x4){0.f, 0.f, 0.f, 0.f};
                int krow = g * 16 + q15;
                #pragma unroll
                for (int kk = 0; kk < 2; ++kk) {
                    Frag8 kf = *(const Frag8*)&Ks[krow * 64 + (((kk * 4 + g2) ^ (krow & 7)) * 8)];
                    sacc[g] = __builtin_amdgcn_mfma_f32_16x16x32_bf16(
                        kf.b, qf[s][kk].b, sacc[g], 0, 0, 0);
                }
            }
            if (j == 2 * qt + s) {   // diagonal tile of this q-set
                #pragma unroll
                for (int g = 0; g < 4; ++g)
                    #pragma unroll
                    for (int r = 0; r < 4; ++r)
                        if (g * 16 + g2 * 4 + r > w * 16 + q15) sacc[g][r] = -1e30f;
            }

            // ---- online softmax ----
            float mt = -INFINITY;
            #pragma unroll
            for (int g = 0; g < 4; ++g)
                #pragma unroll
                for (int r = 0; r < 4; ++r) mt = fmaxf(mt, sacc[g][r]);
            mt = fmaxf(mt, __shfl_xor(mt, 16));
            mt = fmaxf(mt, __shfl_xor(mt, 32));
            float mnew = fmaxf(m_run[s], mt);
            float fsc = __expf(m_run[s] - mnew);
            m_run[s] = mnew;
            float psum = 0.f;
            #pragma unroll
            for (int g = 0; g < 4; ++g) {
                float p0 = __expf(sacc[g][0] - mnew);
                float p1 = __expf(sacc[g][1] - mnew);
                float p2 = __expf(sacc[g][2] - mnew);
                float p3 = __expf(sacc[g][3] - mnew);
                psum += (p0 + p1) + (p2 + p3);
                uint2 pk;
                pk.x = (unsigned int)f2bf(p0) | ((unsigned int)f2bf(p1) << 16);
                pk.y = (unsigned int)f2bf(p2) | ((unsigned int)f2bf(p3) << 16);
                *(uint2*)&Pw[q15 * 128 + ((32 * g + 8 * g2) ^ swp)] = pk;
            }
            psum += __shfl_xor(psum, 16);
            psum += __shfl_xor(psum, 32);
            l_run[s] = l_run[s] * fsc + psum;

            float fr[4];
            #pragma unroll
            for (int r = 0; r < 4; ++r) fr[r] = __shfl(fsc, g2 * 4 + r);
            #pragma unroll
            for (int dg = 0; dg < 4; ++dg)
                #pragma unroll
                for (int r = 0; r < 4; ++r) acco[s][dg][r] *= fr[r];

            // ---- PV ----
            Frag8 pa[2];
            #pragma unroll
            for (int kk = 0; kk < 2; ++kk)
                pa[kk] = *(const Frag8*)&Pw[q15 * 128 + ((64 * kk + 16 * g2) ^ swp)];
            #pragma unroll
            for (int dg = 0; dg < 4; ++dg) {
                int vrow = dg * 16 + q15;
                #pragma unroll
                for (int kk = 0; kk < 2; ++kk) {
                    Frag8 vf = *(const Frag8*)&VTs[vrow * 64 + (((kk * 4 + g2) ^ (vrow & 7)) * 8)];
                    acco[s][dg] = __builtin_amdgcn_mfma_f32_16x16x32_bf16(
                        pa[kk].b, vf.b, acco[s][dg], 0, 0, 0);
                }
            }
        }
    }

    // ---- epilogue ----
    #pragma unroll
    for (int s = 0; s < 2; ++s) {
        float lr[4];
        #pragma unroll
        for (int r = 0; r < 4; ++r) lr[r] = 1.f / __shfl(l_run[s], g2 * 4 + r);
        const int qbase = qt * 128 + s * 64 + w * 16;
        #pragma unroll
        for (int dg = 0; dg < 4; ++dg)
            #pragma unroll
            for (int r = 0; r < 4; ++r)
                out[((size_t)(b * Tt + qbase + g2 * 4 + r)) * Cc + h * 64 + dg * 16 + q15] =
                    f2bf(acco[s][dg][r] * lr[r]);
    }
}

// ---------------------------------------------------------------------------
// Launch
// ---------------------------------------------------------------------------
extern "C" void kernel_launch(void* const* d_in, const int* in_sizes, int n_in,
                              void* d_out, int out_size, void* d_ws, size_t ws_size,
                              hipStream_t stream) {
    const float* x      = (const float*)d_in[0];
    const float* w_qkv  = (const float*)d_in[2];
    const float* b_qkv  = (const float*)d_in[3];
    const float* w_o    = (const float*)d_in[4];
    const float* b_o    = (const float*)d_in[5];
    const float* rms_w  = (const float*)d_in[6];
    float* out = (float*)d_out;

    char* ws = (char*)d_ws;
    u16*   xn_bf   = (u16*)ws;                                   // 8 MB [0,8)
    u16*   Kb      = (u16*)(ws + (size_t)(8 << 20));             // 8 MB [8,16)
    u16*   Vt      = (u16*)(ws + (size_t)(16 << 20));            // 8 MB [16,24)
    u16*   Qb      = (u16*)(ws + (size_t)(24 << 20));            // 8 MB [24,32)
    u16*   qkvb    = (u16*)(ws + (size_t)(32 << 20));            // 24 MB [32,56)
    u16*   wqkv_bf = (u16*)(ws + (size_t)(56 << 20));            // 6 MB [56,62)
    u16*   wo_bf   = (u16*)(ws + (size_t)(62 << 20));            // 2 MB [62,64)
    float* cosT    = (float*)(ws + (size_t)(64 << 20));          // 256 KB
    float* sinT    = (float*)(ws + (size_t)(64 << 20) + (1 << 18));
    u16*   attn_bf = xn_bf;   // xn dead after QKV GEMM

    rope_tables_k<<<dim3(Tt / 2), dim3(64), 0, stream>>>(cosT, sinT);
    f2bf_arr_k<<<dim3(3 * Cc * Cc / 1024), dim3(256), 0, stream>>>(w_qkv, wqkv_bf);
    f2bf_arr_k<<<dim3(Cc * Cc / 1024), dim3(256), 0, stream>>>(w_o, wo_bf);
    rmsnorm_k<<<dim3(M_ROWS), dim3(256), 0, stream>>>(x, rms_w, xn_bf);
    gemm_mfma_k<true><<<dim3(3 * Cc / 128, M_ROWS / 128), dim3(256), 0, stream>>>(
        xn_bf, wqkv_bf, b_qkv, qkvb, M_ROWS, 3 * Cc, Cc);
    rope_pack_k<<<dim3(Tt / 64, Hh, Bb), dim3(256), 0, stream>>>(
        qkvb, cosT, sinT, Qb, Kb, Vt);
    attn_mfma_k<<<dim3(Tt / 128, Hh, Bb), dim3(256), 0, stream>>>(Qb, Kb, Vt, attn_bf);
    gemm_mfma_k<false><<<dim3(Cc / 128, M_ROWS / 128), dim3(256), 0, stream>>>(
        attn_bf, wo_bf, b_o, out, M_ROWS, Cc, Cc);
}

// Round 9
// 163.422 us; speedup vs baseline: 12.0091x; 1.1017x over previous
//
#include <hip/hip_runtime.h>
#include <math.h>

// Problem constants: B=2, T=2048, C=1024, H=16, D=64
constexpr int Bb = 2;
constexpr int Tt = 2048;
constexpr int Cc = 1024;
constexpr int Hh = 16;
constexpr int M_ROWS = Bb * Tt;          // 4096
constexpr float EPSV = 1e-5f;

typedef __attribute__((ext_vector_type(4))) float f32x4;
typedef __attribute__((ext_vector_type(8))) __bf16 bf16x8;
using u16 = unsigned short;

union Frag8 {
    u16 u[8];
    unsigned int ui[4];
    uint4 v;
    bf16x8 b;
};

// fp32 -> bf16 round-to-nearest-even
__device__ __forceinline__ u16 f2bf(float f) {
    union { float f; unsigned int u; } c;
    c.f = f;
    unsigned int r = (c.u + 0x7fffu + ((c.u >> 16) & 1u)) >> 16;
    return (u16)r;
}
__device__ __forceinline__ float bf2f(u16 u) {
    union { unsigned int i; float f; } c;
    c.i = ((unsigned int)u) << 16;
    return c.f;
}

// async global->LDS, 16 B per lane; LDS dest = wave-uniform base + lane*16
__device__ __forceinline__ void gload_lds16(const void* g, void* l) {
    __builtin_amdgcn_global_load_lds(
        (__attribute__((address_space(1))) void*)const_cast<void*>(g),
        (__attribute__((address_space(3))) void*)l, 16, 0, 0);
}

// ---------------------------------------------------------------------------
// RoPE tables: cos/sin [T][32]
// ---------------------------------------------------------------------------
__global__ __launch_bounds__(64) void rope_tables_k(float* __restrict__ cosT,
                                                    float* __restrict__ sinT) {
    int tid = threadIdx.x;
    int t = blockIdx.x * 2 + (tid >> 5);
    int j = tid & 31;
    float inv = exp2f(-(float)j * (log2f(10000.0f) / 32.0f));
    float a = (float)t * inv;
    cosT[t * 32 + j] = cosf(a);
    sinT[t * 32 + j] = sinf(a);
}

// ---------------------------------------------------------------------------
// fp32 -> bf16 array convert (for weights), 4 elems/thread
// ---------------------------------------------------------------------------
__global__ __launch_bounds__(256) void f2bf_arr_k(const float* __restrict__ in,
                                                  u16* __restrict__ out) {
    int i = (blockIdx.x * 256 + threadIdx.x) * 4;
    float4 v = *(const float4*)&in[i];
    ushort4 o;
    o.x = f2bf(v.x); o.y = f2bf(v.y); o.z = f2bf(v.z); o.w = f2bf(v.w);
    *(ushort4*)&out[i] = o;
}

// ---------------------------------------------------------------------------
// RMSNorm: one block per row of C=1024; 256 threads x float4 -> bf16 out
// ---------------------------------------------------------------------------
__global__ __launch_bounds__(256) void rmsnorm_k(const float* __restrict__ x,
                                                 const float* __restrict__ w,
                                                 u16* __restrict__ xn) {
    int row = blockIdx.x;
    int tid = threadIdx.x;
    const float* xr = x + (size_t)row * Cc;
    float4 v = *(const float4*)&xr[tid * 4];
    float ss = v.x * v.x + v.y * v.y + v.z * v.z + v.w * v.w;
    #pragma unroll
    for (int off = 32; off > 0; off >>= 1) ss += __shfl_down(ss, off);
    __shared__ float ws_[4];
    if ((tid & 63) == 0) ws_[tid >> 6] = ss;
    __syncthreads();
    float tot = ws_[0] + ws_[1] + ws_[2] + ws_[3];
    float r = rsqrtf(tot * (1.0f / (float)Cc) + EPSV);
    float4 wv = *(const float4*)&w[tid * 4];
    ushort4 o;
    o.x = f2bf(v.x * r * wv.x);
    o.y = f2bf(v.y * r * wv.y);
    o.z = f2bf(v.z * r * wv.z);
    o.w = f2bf(v.w * r * wv.w);
    *(ushort4*)&xn[(size_t)row * Cc + tid * 4] = o;
}

// ---------------------------------------------------------------------------
// bf16 MFMA GEMM: O[M][N] = A[M][K]_bf16 * W[N][K]_bf16^T + bias[N].
// Output fp32 or bf16 (template). 128x128 tile, BK=64, 4 waves (2x2).
// global_load_lds staging with source-chunk XOR swizzle (rule #21).
// ---------------------------------------------------------------------------
template<bool BF16OUT>
__global__ __launch_bounds__(256) void gemm_mfma_k(const u16* __restrict__ A,
                                                   const u16* __restrict__ W,
                                                   const float* __restrict__ bias,
                                                   void* __restrict__ Ov,
                                                   int M, int N, int K) {
    __shared__ __align__(16) u16 As[128 * 64];   // 16 KB
    __shared__ __align__(16) u16 Bs[128 * 64];   // 16 KB

    const int tid = threadIdx.x;
    const int w = tid >> 6;
    const int l = tid & 63;
    const int wr = w >> 1;
    const int wc = w & 1;
    const int q = l & 15;
    const int g = l >> 4;

    const int m0 = blockIdx.y * 128;
    const int n0 = blockIdx.x * 128;

    const int srow_in = l >> 3;
    const int p_chunk = l & 7;

    f32x4 acc[4][4];
    #pragma unroll
    for (int i = 0; i < 4; ++i)
        #pragma unroll
        for (int j = 0; j < 4; ++j)
            acc[i][j] = (f32x4){0.f, 0.f, 0.f, 0.f};

    const int nkt = K >> 6;
    for (int kt = 0; kt < nkt; ++kt) {
        const int k0 = kt << 6;
        __syncthreads();
        #pragma unroll
        for (int s = 0; s < 4; ++s) {
            int blk = s * 4 + w;
            int r = blk * 8 + srow_in;
            int c = p_chunk ^ (r & 7);
            gload_lds16(A + (size_t)(m0 + r) * K + k0 + c * 8, &As[blk * 512]);
            gload_lds16(W + (size_t)(n0 + r) * K + k0 + c * 8, &Bs[blk * 512]);
        }
        __syncthreads();

        #pragma unroll
        for (int kk = 0; kk < 2; ++kk) {
            Frag8 af[4], bf[4];
            const int ca = kk * 4 + g;
            #pragma unroll
            for (int i = 0; i < 4; ++i) {
                int ra = wr * 64 + i * 16 + q;
                af[i] = *(const Frag8*)&As[ra * 64 + ((ca ^ (ra & 7)) * 8)];
                int rb = wc * 64 + i * 16 + q;
                bf[i] = *(const Frag8*)&Bs[rb * 64 + ((ca ^ (rb & 7)) * 8)];
            }
            #pragma unroll
            for (int i = 0; i < 4; ++i)
                #pragma unroll
                for (int j = 0; j < 4; ++j)
                    acc[i][j] = __builtin_amdgcn_mfma_f32_16x16x32_bf16(
                        af[i].b, bf[j].b, acc[i][j], 0, 0, 0);
        }
    }

    #pragma unroll
    for (int i = 0; i < 4; ++i) {
        int row = m0 + wr * 64 + i * 16 + g * 4;
        #pragma unroll
        for (int j = 0; j < 4; ++j) {
            int col = n0 + wc * 64 + j * 16 + q;
            float bb = bias[col];
            #pragma unroll
            for (int r2 = 0; r2 < 4; ++r2) {
                float val = acc[i][j][r2] + bb;
                if (BF16OUT)
                    ((u16*)Ov)[(size_t)(row + r2) * N + col] = f2bf(val);
                else
                    ((float*)Ov)[(size_t)(row + r2) * N + col] = val;
            }
        }
    }
}

// ---------------------------------------------------------------------------
// RoPE + repack: qkv_bf16 [b,t,3,h,64] -> Qb/Kb [b,h,t,64] bf16 (Q pre-scaled
// by 1/8), Vt [b,h,64,T] bf16 (transposed via LDS).
// Grid (T/64, H, B), 256 threads.
// ---------------------------------------------------------------------------
__global__ __launch_bounds__(256) void rope_pack_k(const u16* __restrict__ qkv,
                                                   const float* __restrict__ cosT,
                                                   const float* __restrict__ sinT,
                                                   u16* __restrict__ Qb,
                                                   u16* __restrict__ Kb,
                                                   u16* __restrict__ Vt) {
    const int t0 = blockIdx.x * 64;
    const int h = blockIdx.y, b = blockIdx.z;
    const int t = threadIdx.x;
    const int bh = b * Hh + h;
    __shared__ u16 Vs[64 * 64];

    // ---- stage V tile to LDS (row-major, bf16 passthrough) ----
    {
        int row = t >> 2, d16 = (t & 3) * 16;
        const u16* vp = qkv + (size_t)(b * Tt + t0 + row) * 3072 + 2048 + h * 64 + d16;
        *(uint4*)&Vs[row * 64 + d16]     = *(const uint4*)vp;
        *(uint4*)&Vs[row * 64 + d16 + 8] = *(const uint4*)(vp + 8);
    }

    // ---- RoPE on Q and K, head-major bf16 out ----
    {
        int row = t >> 2, d0 = (t & 3) * 8;
        size_t rb = (size_t)(b * Tt + t0 + row) * 3072 + h * 64;
        const u16* qp = qkv + rb;
        const u16* kp = qkv + rb + 1024;
        Frag8 qlo, qhi, klo, khi;
        qlo.v = *(const uint4*)&qp[d0];
        qhi.v = *(const uint4*)&qp[d0 + 32];
        klo.v = *(const uint4*)&kp[d0];
        khi.v = *(const uint4*)&kp[d0 + 32];
        const float* cp = &cosT[(t0 + row) * 32 + d0];
        const float* sp = &sinT[(t0 + row) * 32 + d0];
        float4 c0 = *(const float4*)cp, c1 = *(const float4*)(cp + 4);
        float4 s0 = *(const float4*)sp, s1 = *(const float4*)(sp + 4);
        float cc[8] = {c0.x, c0.y, c0.z, c0.w, c1.x, c1.y, c1.z, c1.w};
        float ss[8] = {s0.x, s0.y, s0.z, s0.w, s1.x, s1.y, s1.z, s1.w};
        Frag8 oql, oqh, okl, okh;
        #pragma unroll
        for (int i = 0; i < 8; ++i) {
            float ql = bf2f(qlo.u[i]), qh = bf2f(qhi.u[i]);
            float kl = bf2f(klo.u[i]), kh = bf2f(khi.u[i]);
            oql.u[i] = f2bf((ql * cc[i] - qh * ss[i]) * 0.125f);
            oqh.u[i] = f2bf((qh * cc[i] + ql * ss[i]) * 0.125f);
            okl.u[i] = f2bf(kl * cc[i] - kh * ss[i]);
            okh.u[i] = f2bf(kh * cc[i] + kl * ss[i]);
        }
        u16* qd = Qb + ((size_t)bh * Tt + t0 + row) * 64;
        u16* kd = Kb + ((size_t)bh * Tt + t0 + row) * 64;
        *(uint4*)&qd[d0]      = oql.v;
        *(uint4*)&qd[d0 + 32] = oqh.v;
        *(uint4*)&kd[d0]      = okl.v;
        *(uint4*)&kd[d0 + 32] = okh.v;
    }
    __syncthreads();

    // ---- V transpose out: Vt[bh][d][t] ----
    {
        int d = t >> 2, kq = (t & 3) * 16;
        Frag8 a, b2;
        #pragma unroll
        for (int j = 0; j < 8; ++j)  a.u[j]  = Vs[(kq + j) * 64 + d];
        #pragma unroll
        for (int j = 0; j < 8; ++j)  b2.u[j] = Vs[(kq + 8 + j) * 64 + d];
        u16* vd = Vt + ((size_t)bh * 64 + d) * Tt + t0 + kq;
        *(uint4*)&vd[0] = a.v;
        *(uint4*)&vd[8] = b2.v;
    }
}

// ---------------------------------------------------------------------------
// MFMA flash attention v3. Block = 8 waves (512 thr), one (b,h), 128 q rows.
// Wave w: q-set s = w>>2 (0..1), row-group w4 = w&3 (16 rows). KVBLK=64.
// K and V^T staged via global_load_lds (2 issues/wave, source-chunk XOR
// swizzle, linear LDS dest). Swapped QK^T; P via per-wave LDS buffer.
// ---------------------------------------------------------------------------
__global__ __launch_bounds__(512) void attn_mfma_k(const u16* __restrict__ Qb,
                                                   const u16* __restrict__ Kb,
                                                   const u16* __restrict__ Vt,
                                                   u16* __restrict__ out) {
    const int qt = (gridDim.x - 1) - blockIdx.x;   // heavy tiles first
    const int h = blockIdx.y, b = blockIdx.z;
    const int t = threadIdx.x;
    const int w = t >> 6;        // wave 0..7
    const int s = w >> 2;        // q-set 0..1
    const int w4 = w & 3;        // row-group within set
    const int l = t & 63;
    const int q15 = l & 15;
    const int g2 = l >> 4;
    const int swp = (q15 & 7) << 4;
    const int bh = b * Hh + h;

    __shared__ __align__(16) u16 Ks[64 * 64];    // 8 KB, chunk-swizzled
    __shared__ __align__(16) u16 VTs[64 * 64];   // 8 KB, chunk-swizzled
    __shared__ __align__(16) char Pws[8 * 2048]; // per-wave P buffer, 16 KB
    char* Pw = Pws + w * 2048;

    // ---- Q fragments for this wave's q-set (scale pre-folded) ----
    Frag8 qf[2];
    {
        int qrow = qt * 128 + s * 64 + w4 * 16 + q15;
        const u16* qp = Qb + ((size_t)bh * Tt + qrow) * 64;
        qf[0] = *(const Frag8*)&qp[g2 * 8];
        qf[1] = *(const Frag8*)&qp[32 + g2 * 8];
    }

    f32x4 acco[4];
    #pragma unroll
    for (int dg = 0; dg < 4; ++dg) acco[dg] = (f32x4){0.f, 0.f, 0.f, 0.f};
    float m_run = -INFINITY, l_run = 0.f;

    const int srow = l >> 3;      // 0..7
    const int cph = l & 7;        // physical 16B chunk
    const int rr = w * 8 + srow;  // row 0..63 of the 64-row tile
    const int cl = cph ^ (rr & 7);
    const u16* Kbase = Kb + (size_t)bh * Tt * 64;
    const u16* Vbase = Vt + (size_t)bh * 64 * Tt;

    const int jmax = 2 * qt + 1;
    for (int j = 0; j <= jmax; ++j) {
        __syncthreads();
        // ---- stage K tile [64key][64d] and V^T tile [64d][64key] ----
        gload_lds16(Kbase + (size_t)(j * 64 + rr) * 64 + cl * 8, &Ks[w * 8 * 64]);
        gload_lds16(Vbase + (size_t)rr * Tt + j * 64 + cl * 8, &VTs[w * 8 * 64]);
        __syncthreads();

        if (!(s == 0 && j == jmax)) {   // skip fully-masked half-tile
            // ---- QK^T (swapped): S^T[key][q] ----
            f32x4 sacc[4];
            #pragma unroll
            for (int g = 0; g < 4; ++g) {
                sacc[g] = (f32x4){0.f, 0.f, 0.f, 0.f};
                int krow = g * 16 + q15;
                #pragma unroll
                for (int kk = 0; kk < 2; ++kk) {
                    Frag8 kf = *(const Frag8*)&Ks[krow * 64 + (((kk * 4 + g2) ^ (krow & 7)) * 8)];
                    sacc[g] = __builtin_amdgcn_mfma_f32_16x16x32_bf16(
                        kf.b, qf[kk].b, sacc[g], 0, 0, 0);
                }
            }
            if (j == 2 * qt + s) {   // diagonal tile of this q-set
                #pragma unroll
                for (int g = 0; g < 4; ++g)
                    #pragma unroll
                    for (int r = 0; r < 4; ++r)
                        if (g * 16 + g2 * 4 + r > w4 * 16 + q15) sacc[g][r] = -1e30f;
            }

            // ---- online softmax ----
            float mt = -INFINITY;
            #pragma unroll
            for (int g = 0; g < 4; ++g)
                #pragma unroll
                for (int r = 0; r < 4; ++r) mt = fmaxf(mt, sacc[g][r]);
            mt = fmaxf(mt, __shfl_xor(mt, 16));
            mt = fmaxf(mt, __shfl_xor(mt, 32));
            float mnew = fmaxf(m_run, mt);
            float fsc = __expf(m_run - mnew);
            m_run = mnew;
            float psum = 0.f;
            #pragma unroll
            for (int g = 0; g < 4; ++g) {
                float p0 = __expf(sacc[g][0] - mnew);
                float p1 = __expf(sacc[g][1] - mnew);
                float p2 = __expf(sacc[g][2] - mnew);
                float p3 = __expf(sacc[g][3] - mnew);
                psum += (p0 + p1) + (p2 + p3);
                uint2 pk;
                pk.x = (unsigned int)f2bf(p0) | ((unsigned int)f2bf(p1) << 16);
                pk.y = (unsigned int)f2bf(p2) | ((unsigned int)f2bf(p3) << 16);
                *(uint2*)&Pw[q15 * 128 + ((32 * g + 8 * g2) ^ swp)] = pk;
            }
            psum += __shfl_xor(psum, 16);
            psum += __shfl_xor(psum, 32);
            l_run = l_run * fsc + psum;

            float fr[4];
            #pragma unroll
            for (int r = 0; r < 4; ++r) fr[r] = __shfl(fsc, g2 * 4 + r);
            #pragma unroll
            for (int dg = 0; dg < 4; ++dg)
                #pragma unroll
                for (int r = 0; r < 4; ++r) acco[dg][r] *= fr[r];

            // ---- PV ----
            Frag8 pa[2];
            #pragma unroll
            for (int kk = 0; kk < 2; ++kk)
                pa[kk] = *(const Frag8*)&Pw[q15 * 128 + ((64 * kk + 16 * g2) ^ swp)];
            #pragma unroll
            for (int dg = 0; dg < 4; ++dg) {
                int vrow = dg * 16 + q15;
                #pragma unroll
                for (int kk = 0; kk < 2; ++kk) {
                    Frag8 vf = *(const Frag8*)&VTs[vrow * 64 + (((kk * 4 + g2) ^ (vrow & 7)) * 8)];
                    acco[dg] = __builtin_amdgcn_mfma_f32_16x16x32_bf16(
                        pa[kk].b, vf.b, acco[dg], 0, 0, 0);
                }
            }
        }
    }

    // ---- epilogue ----
    float lr[4];
    #pragma unroll
    for (int r = 0; r < 4; ++r) lr[r] = 1.f / __shfl(l_run, g2 * 4 + r);
    const int qbase = qt * 128 + s * 64 + w4 * 16;
    #pragma unroll
    for (int dg = 0; dg < 4; ++dg)
        #pragma unroll
        for (int r = 0; r < 4; ++r)
            out[((size_t)(b * Tt + qbase + g2 * 4 + r)) * Cc + h * 64 + dg * 16 + q15] =
                f2bf(acco[dg][r] * lr[r]);
}

// ---------------------------------------------------------------------------
// Launch
// ---------------------------------------------------------------------------
extern "C" void kernel_launch(void* const* d_in, const int* in_sizes, int n_in,
                              void* d_out, int out_size, void* d_ws, size_t ws_size,
                              hipStream_t stream) {
    const float* x      = (const float*)d_in[0];
    const float* w_qkv  = (const float*)d_in[2];
    const float* b_qkv  = (const float*)d_in[3];
    const float* w_o    = (const float*)d_in[4];
    const float* b_o    = (const float*)d_in[5];
    const float* rms_w  = (const float*)d_in[6];
    float* out = (float*)d_out;

    char* ws = (char*)d_ws;
    u16*   xn_bf   = (u16*)ws;                                   // 8 MB [0,8)
    u16*   Kb      = (u16*)(ws + (size_t)(8 << 20));             // 8 MB [8,16)
    u16*   Vt      = (u16*)(ws + (size_t)(16 << 20));            // 8 MB [16,24)
    u16*   Qb      = (u16*)(ws + (size_t)(24 << 20));            // 8 MB [24,32)
    u16*   qkvb    = (u16*)(ws + (size_t)(32 << 20));            // 24 MB [32,56)
    u16*   wqkv_bf = (u16*)(ws + (size_t)(56 << 20));            // 6 MB [56,62)
    u16*   wo_bf   = (u16*)(ws + (size_t)(62 << 20));            // 2 MB [62,64)
    float* cosT    = (float*)(ws + (size_t)(64 << 20));          // 256 KB
    float* sinT    = (float*)(ws + (size_t)(64 << 20) + (1 << 18));
    u16*   attn_bf = xn_bf;   // xn dead after QKV GEMM

    rope_tables_k<<<dim3(Tt / 2), dim3(64), 0, stream>>>(cosT, sinT);
    f2bf_arr_k<<<dim3(3 * Cc * Cc / 1024), dim3(256), 0, stream>>>(w_qkv, wqkv_bf);
    f2bf_arr_k<<<dim3(Cc * Cc / 1024), dim3(256), 0, stream>>>(w_o, wo_bf);
    rmsnorm_k<<<dim3(M_ROWS), dim3(256), 0, stream>>>(x, rms_w, xn_bf);
    gemm_mfma_k<true><<<dim3(3 * Cc / 128, M_ROWS / 128), dim3(256), 0, stream>>>(
        xn_bf, wqkv_bf, b_qkv, qkvb, M_ROWS, 3 * Cc, Cc);
    rope_pack_k<<<dim3(Tt / 64, Hh, Bb), dim3(256), 0, stream>>>(
        qkvb, cosT, sinT, Qb, Kb, Vt);
    attn_mfma_k<<<dim3(Tt / 128, Hh, Bb), dim3(512), 0, stream>>>(Qb, Kb, Vt, attn_bf);
    gemm_mfma_k<false><<<dim3(Cc / 128, M_ROWS / 128), dim3(256), 0, stream>>>(
        attn_bf, wo_bf, b_o, out, M_ROWS, Cc, Cc);
}